// Round 4
// baseline (13773.967 us; speedup 1.0000x reference)
//
#include <hip/hip_runtime.h>
#include <hip/hip_bf16.h>
#include <cstdint>
#include <cstddef>

// ============================================================================
// AutoregressiveDecoder on MI355X — bf16x3 (hi/lo split) MFMA design.
//
// Key facts exploited:
//  * x = [pos, context]: context part of GRU0's input gates is constant over
//    the 60 steps -> precompute gi_ctx = ctx @ w_ih0[:,2:].T once (prologue).
//  * Batch rows independent -> block owns 64 rows, runs all 60 steps locally.
//  * GEMMs run transposed (gates^T = W @ h^T) with v_mfma_f32_32x32x16_bf16 so
//    D cols (lane&31) == batch row == B-frag lane mapping.
//  * fp32 accuracy recovered via bf16 hi/lo split: 3 MFMAs per logical tile
//    (hi*hi + hi*lo + lo*hi), rel err ~2^-16.
//  * State h0/h1 kept in LDS as pre-split hi/lo B-fragments (64KB each).
//  * Weights packed once into frag-linear hi/lo layout; A-frags read straight
//    from L2 (2.36MB/step/CU ~= 43 B/cyc < 56 B/cyc measured L2 ceiling).
// ============================================================================

typedef __attribute__((ext_vector_type(8)))  short bf16x8;   // 8 bf16 (guide-verified operand type)
typedef __attribute__((ext_vector_type(16))) float f32x16;
typedef __attribute__((ext_vector_type(4)))  float f32x4;
typedef unsigned short ushort_t;
typedef unsigned int   uint32;

#define MFMA_BF16(A,B,C) __builtin_amdgcn_mfma_f32_32x32x16_bf16(A,B,C,0,0,0)
#define MMA3(ACC, AH, AL, BH, BL)            \
  ACC = MFMA_BF16(AH, BH, ACC);              \
  ACC = MFMA_BF16(AH, BL, ACC);              \
  ACC = MFMA_BF16(AL, BH, ACC);

#define TSTEPS 60
#define CB_OFF 3932160          // cholesky base offset in d_out (32768*60*2)

// ---- workspace layout (bytes) ----
#define WPK0 0u                 // w_hh0 packed  24*16*2048 = 786432
#define WPK1 786432u            // w_ih1 packed
#define WPK2 1572864u           // w_hh1 packed
#define WPKI 2359296u           // w_init packed 16*32*2048 = 1048576
#define WPKG 3407872u           // w_ih0[:,2:] packed 24*32*2048 = 1572864
#define JCON 4980736u           // jconst[768] float4: {b_hh0, wp0, wp1, w4}
#define OUTW 4993024u           // outw[256][8] f32: {wpos0,wpos1,wchol0,wchol1,wchol2,0,0,0}
#define NTWO 5001216u           // n2[256] = b_hh1[512+k]
#define GIWS 5002240u           // gi spill: 512 blocks * 196608 B
#define GI_PER_BLK 196608u

// ---- LDS layout (bytes) ----
#define OFF_H0 0                // h0 state frags: [c16][p2][s2][lane64][16B] = 65536
#define OFF_H1 65536
#define OFF_BUF 131072          // reduce buf [8][64][8] f32 = 16384
#define OFF_POS 147456          // posbuf [64][2] f32 = 512
#define SMEM_BYTES 147968

// ---------------- helpers ----------------
__device__ __forceinline__ ushort_t f2bf(float x){
  uint32 u = __builtin_bit_cast(uint32, x);
  u += 0x7fffu + ((u >> 16) & 1u);
  return (ushort_t)(u >> 16);
}
__device__ __forceinline__ float bf2f(ushort_t b){
  uint32 u = ((uint32)b) << 16;
  return __builtin_bit_cast(float, u);
}
__device__ __forceinline__ void zero16(f32x16& a){
  #pragma unroll
  for (int i=0;i<16;i++) a[i] = 0.f;
}

#define LOG2E 1.44269504088896340736f
#define LN2   0.69314718055994530942f
__device__ __forceinline__ float fexp2(float x){ return __builtin_amdgcn_exp2f(x); }
__device__ __forceinline__ float flog2(float x){ return __builtin_amdgcn_logf(x); }
__device__ __forceinline__ float frcp (float x){ return __builtin_amdgcn_rcpf(x); }
__device__ __forceinline__ float fsig(float x){ return frcp(1.f + fexp2(-LOG2E*x)); }
__device__ __forceinline__ float ftanh(float x){
  float ax = fabsf(x);
  float e  = fexp2(-2.f*LOG2E*ax);
  float t  = (1.f - e)*frcp(1.f + e);
  return copysignf(t, x);
}
__device__ __forceinline__ float fsoftplus(float x){
  float ax = fabsf(x);
  return fmaxf(x, 0.f) + LN2*flog2(1.f + fexp2(-LOG2E*ax));
}

// ---------------- weight packing ----------------
// frag-linear layout: [t][c][p(hi/lo)][lane][8 bf16]; A-frag(lane l) covers
// row j = 32t + (l&31), k = 16c + (l>>5)*8 + r.
__device__ __forceinline__ void pack_unit(const float* __restrict__ src, int stride, int colOff,
                                          char* __restrict__ dst, int NC, int ncLog, int v)
{
  int l = v & 63;
  int c = (v >> 6) & (NC-1);
  int t = v >> (6 + ncLog);
  int j  = 32*t + (l & 31);
  int k0 = 16*c + ((l >> 5) << 3);
  const float* s = src + (size_t)j*stride + colOff + k0;
  uint32 hp[4], lp[4];
  #pragma unroll
  for (int i=0;i<4;i++){
    float x0 = s[2*i], x1 = s[2*i+1];
    ushort_t h0_ = f2bf(x0), h1_ = f2bf(x1);
    ushort_t l0_ = f2bf(x0 - bf2f(h0_)), l1_ = f2bf(x1 - bf2f(h1_));
    hp[i] = (uint32)h0_ | ((uint32)h1_ << 16);
    lp[i] = (uint32)l0_ | ((uint32)l1_ << 16);
  }
  char* d = dst + ((size_t)(t*NC + c))*2048 + (size_t)l*16;
  *(uint4*)d          = make_uint4(hp[0],hp[1],hp[2],hp[3]);
  *(uint4*)(d + 1024) = make_uint4(lp[0],lp[1],lp[2],lp[3]);
}

__global__ void k_pack(const float* __restrict__ w_init, const float* __restrict__ w_ih0,
                       const float* __restrict__ w_hh0, const float* __restrict__ b_hh0,
                       const float* __restrict__ w_ih1, const float* __restrict__ w_hh1,
                       const float* __restrict__ b_ih1, const float* __restrict__ b_hh1,
                       const float* __restrict__ w_pos, const float* __restrict__ w_chol,
                       char* __restrict__ ws)
{
  int u = blockIdx.x*256 + threadIdx.x;
  if (u < 73728){                       // 3x (768x256) GRU weights
    int seg = u / 24576; int v = u % 24576;
    const float* src = (seg==0) ? w_hh0 : ((seg==1) ? w_ih1 : w_hh1);
    char* dst = ws + ((seg==0) ? WPK0 : ((seg==1) ? WPK1 : WPK2));
    pack_unit(src, 256, 0, dst, 16, 4, v);
  } else if (u < 106496){               // w_init 512x512
    pack_unit(w_init, 512, 0, ws + WPKI, 32, 5, u - 73728);
  } else if (u < 155648){               // w_ih0[:,2:514] 768x512
    pack_unit(w_ih0, 514, 2, ws + WPKG, 32, 5, u - 106496);
  } else if (u < 156416){               // jconst
    int j = u - 155648;
    float w4 = (j < 512) ? (b_ih1[j] + b_hh1[j]) : b_ih1[j];
    ((float4*)(ws + JCON))[j] =
        make_float4(b_hh0[j], w_ih0[(size_t)j*514 + 0], w_ih0[(size_t)j*514 + 1], w4);
  } else if (u < 156672){               // outw
    int k = u - 156416;
    ((float4*)(ws + OUTW))[2*k]   = make_float4(w_pos[k], w_pos[256+k], w_chol[k], w_chol[256+k]);
    ((float4*)(ws + OUTW))[2*k+1] = make_float4(w_chol[512+k], 0.f, 0.f, 0.f);
  } else if (u < 156928){               // n2 = b_hh1 n-part
    int k = u - 156672;
    ((float*)(ws + NTWO))[k] = b_hh1[512+k];
  }
}

// ---------------- main-kernel building blocks ----------------

// GEMM over NCHUNK k-chunks: A from packed global weights (tiles w, w+8, ...),
// B hi/lo frags from LDS at sbase. acc[i][s] += sum_k W.hi/lo * H.hi/lo.
template<int NTILE, int NCHUNK>
__device__ __forceinline__ void gemm_frag(const char* __restrict__ apk, int w, int l,
                                          const char* __restrict__ sbase,
                                          f32x16 (&acc)[NTILE][2])
{
  #pragma unroll 4
  for (int c=0;c<NCHUNK;c++){
    bf16x8 A[NTILE][2];
    #pragma unroll
    for (int i=0;i<NTILE;i++){
      const char* p = apk + ((size_t)((w+8*i)*NCHUNK + c))*2048 + (size_t)l*16;
      A[i][0] = *(const bf16x8*)p;
      A[i][1] = *(const bf16x8*)(p + 1024);
    }
    bf16x8 Bf[2][2];
    #pragma unroll
    for (int s=0;s<2;s++)
      #pragma unroll
      for (int p2=0;p2<2;p2++)
        Bf[s][p2] = *(const bf16x8*)(sbase + ((c*2+p2)*2+s)*1024 + l*16);
    #pragma unroll
    for (int i=0;i<NTILE;i++)
      #pragma unroll
      for (int s=0;s<2;s++){
        MMA3(acc[i][s], A[i][0], A[i][1], Bf[s][0], Bf[s][1]);
      }
  }
}

// read this wave's own state slab back in D-layout (f32 = hi + lo)
__device__ __forceinline__ void readback(const char* __restrict__ hbase, int w, int l,
                                         f32x16 (&ho)[2])
{
  const int L = l >> 5, l31 = l & 31;
  #pragma unroll
  for (int s=0;s<2;s++)
    #pragma unroll
    for (int g=0;g<4;g++){
      int cg = 2*w + (g>>1);
      int lane2 = l31 + 32*(g&1);
      const char* ph = hbase + ((cg*2+0)*2 + s)*1024 + lane2*16 + 8*L;
      const char* pl = hbase + ((cg*2+1)*2 + s)*1024 + lane2*16 + 8*L;
      uint2 hb = *(const uint2*)ph;
      uint2 lb = *(const uint2*)pl;
      ho[s][4*g+0] = bf2f((ushort_t)(hb.x & 0xffff)) + bf2f((ushort_t)(lb.x & 0xffff));
      ho[s][4*g+1] = bf2f((ushort_t)(hb.x >> 16))    + bf2f((ushort_t)(lb.x >> 16));
      ho[s][4*g+2] = bf2f((ushort_t)(hb.y & 0xffff)) + bf2f((ushort_t)(lb.y & 0xffff));
      ho[s][4*g+3] = bf2f((ushort_t)(hb.y >> 16))    + bf2f((ushort_t)(lb.y >> 16));
    }
}

// convert new-h D-layout regs -> hi/lo B-frags, write wave's own state chunks.
// D value for k sits in lane-half (k>>2)&1, reg q=(k&3)|((k>>3)<<2);
// B-frag target: chunk-local c=k>>4(local), r=k&7, lane-half (k>>3)&1.
__device__ __forceinline__ void write_state(char* __restrict__ hbase, int w, int l,
                                            const f32x16 (&hn)[2])
{
  const int L = l >> 5;
  #pragma unroll
  for (int s=0;s<2;s++){
    float loc[16], sw[16];
    #pragma unroll
    for (int q=0;q<16;q++){ loc[q] = hn[s][q]; sw[q] = __shfl_xor(loc[q], 32, 64); }
    #pragma unroll
    for (int c=0;c<2;c++){
      float v[8];
      if (L == 0){
        #pragma unroll
        for (int r=0;r<8;r++){ int q = (r&3) + 8*c;     v[r] = (r<4)  ? loc[q] : sw[q]; }
      } else {
        #pragma unroll
        for (int r=0;r<8;r++){ int q = (r&3) + 8*c + 4; v[r] = (r>=4) ? loc[q] : sw[q]; }
      }
      uint32 hp[4], lp[4];
      #pragma unroll
      for (int i=0;i<4;i++){
        ushort_t h0_ = f2bf(v[2*i]), h1_ = f2bf(v[2*i+1]);
        ushort_t l0_ = f2bf(v[2*i] - bf2f(h0_)), l1_ = f2bf(v[2*i+1] - bf2f(h1_));
        hp[i] = (uint32)h0_ | ((uint32)h1_ << 16);
        lp[i] = (uint32)l0_ | ((uint32)l1_ << 16);
      }
      int cg = 2*w + c;
      *(uint4*)(hbase + ((cg*2+0)*2+s)*1024 + l*16) = make_uint4(hp[0],hp[1],hp[2],hp[3]);
      *(uint4*)(hbase + ((cg*2+1)*2+s)*1024 + l*16) = make_uint4(lp[0],lp[1],lp[2],lp[3]);
    }
  }
}

// ---------------- the persistent decoder kernel ----------------
__global__ __launch_bounds__(512, 2) void decoder_main(
    const float* __restrict__ ctx,
    const float* __restrict__ b_init,
    const float* __restrict__ b_ih0,
    const float* __restrict__ b_pos,
    const float* __restrict__ b_chol,
    const char*  __restrict__ ws,
    char*        __restrict__ gws,
    float*       __restrict__ out)
{
  extern __shared__ char smem[];
  const int tid = threadIdx.x;
  const int w   = tid >> 6;
  const int l   = tid & 63;
  const int L   = l >> 5;
  const int l31 = l & 31;
  const int blk = blockIdx.x;
  const int B0  = blk * 64;
  char* gib = gws + (size_t)blk * GI_PER_BLK;
  const float4* jconst = (const float4*)(ws + JCON);
  const float4* outw   = (const float4*)(ws + OUTW);
  const float*  n2c    = (const float*)(ws + NTWO);
  float* posb = (float*)(smem + OFF_POS);
  float* buff = (float*)(smem + OFF_BUF);

  // ---- prologue A: stage ctx hi/lo B-frags into LDS (aliases state area) ----
  #pragma unroll
  for (int ci=0; ci<4; ci++){
    int c = w + 8*ci;
    #pragma unroll
    for (int s=0;s<2;s++){
      const float* src = ctx + (size_t)(B0 + 32*s + l31)*512 + 16*c + 8*L;
      float4 a0 = *(const float4*)src;
      float4 a1 = *(const float4*)(src + 4);
      float xs[8] = {a0.x,a0.y,a0.z,a0.w,a1.x,a1.y,a1.z,a1.w};
      uint32 hp[4], lp[4];
      #pragma unroll
      for (int i=0;i<4;i++){
        ushort_t h0_ = f2bf(xs[2*i]), h1_ = f2bf(xs[2*i+1]);
        ushort_t l0_ = f2bf(xs[2*i] - bf2f(h0_)), l1_ = f2bf(xs[2*i+1] - bf2f(h1_));
        hp[i] = (uint32)h0_ | ((uint32)h1_ << 16);
        lp[i] = (uint32)l0_ | ((uint32)l1_ << 16);
      }
      *(uint4*)(smem + ((c*2+0)*2 + s)*1024 + l*16) = make_uint4(hp[0],hp[1],hp[2],hp[3]);
      *(uint4*)(smem + ((c*2+1)*2 + s)*1024 + l*16) = make_uint4(lp[0],lp[1],lp[2],lp[3]);
    }
  }
  __syncthreads();

  // ---- prologue B: hid = tanh(ctx @ w_init.T + b_init) ----
  f32x16 hD0[2], hD1[2];
  {
    f32x16 aH[2][2];
    zero16(aH[0][0]); zero16(aH[0][1]); zero16(aH[1][0]); zero16(aH[1][1]);
    gemm_frag<2,32>(ws + WPKI, w, l, smem, aH);
    #pragma unroll
    for (int ti=0; ti<2; ti++)
      #pragma unroll
      for (int s=0;s<2;s++)
        #pragma unroll
        for (int g=0;g<4;g++)
          #pragma unroll
          for (int e=0;e<4;e++){
            int kq = 4*L + e + 8*g;
            int j  = 32*(w + 8*ti) + kq;
            float v = ftanh(aH[ti][s][4*g+e] + b_init[j]);
            if (ti==0) hD0[s][4*g+e] = v; else hD1[s][4*g+e] = v;
          }
  }

  // ---- prologue C: gi_ctx = ctx @ w_ih0[:,2:].T + b_ih0, spilled to ws ----
  {
    f32x16 aG[3][2];
    #pragma unroll
    for (int i=0;i<3;i++){ zero16(aG[i][0]); zero16(aG[i][1]); }
    gemm_frag<3,32>(ws + WPKG, w, l, smem, aG);
    #pragma unroll
    for (int ti=0; ti<3; ti++)
      #pragma unroll
      for (int s=0;s<2;s++)
        #pragma unroll
        for (int g=0;g<4;g++){
          f32x4 qv;
          #pragma unroll
          for (int e=0;e<4;e++){
            int kq = 4*L + e + 8*g;
            int j  = 32*(w + 8*ti) + kq;
            qv[e] = aG[ti][s][4*g+e] + b_ih0[j];
          }
          *(f32x4*)(gib + ((size_t)((w*3 + ti)*2 + s))*4096 + g*1024 + (size_t)l*16) = qv;
        }
  }
  __syncthreads();                       // all ctx-frag reads done

  write_state(smem + OFF_H0, w, l, hD0); // state overwrites ctx area
  write_state(smem + OFF_H1, w, l, hD1);
  if (tid < 128) posb[tid] = 0.f;
  __syncthreads();

  // ---- 60 autoregressive steps ----
  for (int t=0; t<TSTEPS; t++){
    // GRU0: gh0 = w_hh0 @ h0^T
    f32x16 g0[3][2];
    #pragma unroll
    for (int i=0;i<3;i++){ zero16(g0[i][0]); zero16(g0[i][1]); }
    gemm_frag<3,16>(ws + WPK0, w, l, smem + OFF_H0, g0);

    f32x16 ho[2];
    readback(smem + OFF_H0, w, l, ho);
    float p0v[2], p1v[2];
    #pragma unroll
    for (int s=0;s<2;s++){
      float2 pp = *(const float2*)(posb + (32*s + l31)*2);
      p0v[s] = pp.x; p1v[s] = pp.y;
    }

    f32x16 hn0[2];
    #pragma unroll
    for (int g=0;g<4;g++){
      f32x4 gr[2], gz[2], gn[2];
      #pragma unroll
      for (int s=0;s<2;s++){
        const char* gb = gib + ((size_t)((w*3 + 0)*2 + s))*4096 + g*1024 + (size_t)l*16;
        gr[s] = *(const f32x4*)gb;
        gz[s] = *(const f32x4*)(gb + 2*4096);
        gn[s] = *(const f32x4*)(gb + 4*4096);
      }
      #pragma unroll
      for (int e=0;e<4;e++){
        int kq = 4*L + e + 8*g;
        int jr = 32*w + kq;
        float4 jcr = jconst[jr], jcz = jconst[256+jr], jcn = jconst[512+jr];
        #pragma unroll
        for (int s=0;s<2;s++){
          int q = 4*g + e;
          float gi_r = gr[s][e] + jcr.y*p0v[s] + jcr.z*p1v[s];
          float gi_z = gz[s][e] + jcz.y*p0v[s] + jcz.z*p1v[s];
          float gi_n = gn[s][e] + jcn.y*p0v[s] + jcn.z*p1v[s];
          float r = fsig(gi_r + g0[0][s][q] + jcr.x);
          float z = fsig(gi_z + g0[1][s][q] + jcz.x);
          float n = ftanh(gi_n + r*(g0[2][s][q] + jcn.x));
          hn0[s][q] = (1.f - z)*n + z*ho[s][q];
        }
      }
    }
    __syncthreads();                     // S1: all h0/pos reads done
    write_state(smem + OFF_H0, w, l, hn0);
    __syncthreads();                     // S2: new h0 visible

    // GRU1: gi1 = w_ih1 @ h0new^T, gh1 = w_hh1 @ h1^T (r,z summed; n split)
    f32x16 aR[2], aZ[2], aNi[2], aNh[2];
    zero16(aR[0]); zero16(aR[1]); zero16(aZ[0]); zero16(aZ[1]);
    zero16(aNi[0]); zero16(aNi[1]); zero16(aNh[0]); zero16(aNh[1]);
    {
      const char* pk1 = ws + WPK1;
      const char* pk2 = ws + WPK2;
      #pragma unroll 4
      for (int c=0;c<16;c++){
        bf16x8 A1[3][2], A2[3][2];
        #pragma unroll
        for (int i=0;i<3;i++){
          size_t o = ((size_t)((w+8*i)*16 + c))*2048 + (size_t)l*16;
          A1[i][0] = *(const bf16x8*)(pk1+o); A1[i][1] = *(const bf16x8*)(pk1+o+1024);
          A2[i][0] = *(const bf16x8*)(pk2+o); A2[i][1] = *(const bf16x8*)(pk2+o+1024);
        }
        bf16x8 B0f[2][2], B1f[2][2];
        #pragma unroll
        for (int s=0;s<2;s++)
          #pragma unroll
          for (int p2=0;p2<2;p2++){
            B0f[s][p2] = *(const bf16x8*)(smem + OFF_H0 + ((c*2+p2)*2+s)*1024 + l*16);
            B1f[s][p2] = *(const bf16x8*)(smem + OFF_H1 + ((c*2+p2)*2+s)*1024 + l*16);
          }
        #pragma unroll
        for (int s=0;s<2;s++){
          MMA3(aR[s],  A1[0][0], A1[0][1], B0f[s][0], B0f[s][1]);
          MMA3(aR[s],  A2[0][0], A2[0][1], B1f[s][0], B1f[s][1]);
          MMA3(aZ[s],  A1[1][0], A1[1][1], B0f[s][0], B0f[s][1]);
          MMA3(aZ[s],  A2[1][0], A2[1][1], B1f[s][0], B1f[s][1]);
          MMA3(aNi[s], A1[2][0], A1[2][1], B0f[s][0], B0f[s][1]);
          MMA3(aNh[s], A2[2][0], A2[2][1], B1f[s][0], B1f[s][1]);
        }
      }
    }

    f32x16 h1o[2];
    readback(smem + OFF_H1, w, l, h1o);
    f32x16 hn1[2];
    #pragma unroll
    for (int g=0;g<4;g++)
      #pragma unroll
      for (int e=0;e<4;e++){
        int kq = 4*L + e + 8*g;
        int k  = 32*w + kq;
        float4 jcr = jconst[k], jcz = jconst[256+k], jcn = jconst[512+k];
        float nb = n2c[k];
        #pragma unroll
        for (int s=0;s<2;s++){
          int q = 4*g + e;
          float r = fsig(aR[s][q] + jcr.w);
          float z = fsig(aZ[s][q] + jcz.w);
          float n = ftanh(aNi[s][q] + jcn.w + r*(aNh[s][q] + nb));
          hn1[s][q] = (1.f - z)*n + z*h1o[s][q];
        }
      }
    __syncthreads();                     // S3: all h1 reads done
    write_state(smem + OFF_H1, w, l, hn1);

    // output head partials: pred(2) + chol-z(3) per row
    float part[2][5];
    #pragma unroll
    for (int s=0;s<2;s++){ part[s][0]=part[s][1]=part[s][2]=part[s][3]=part[s][4]=0.f; }
    #pragma unroll
    for (int g=0;g<4;g++)
      #pragma unroll
      for (int e=0;e<4;e++){
        int kq = 4*L + e + 8*g;
        int k  = 32*w + kq;
        float4 o0 = outw[2*k], o1 = outw[2*k+1];
        #pragma unroll
        for (int s=0;s<2;s++){
          float h = hn1[s][4*g+e];
          part[s][0] += h*o0.x; part[s][1] += h*o0.y; part[s][2] += h*o0.z;
          part[s][3] += h*o0.w; part[s][4] += h*o1.x;
        }
      }
    #pragma unroll
    for (int s=0;s<2;s++)
      #pragma unroll
      for (int o=0;o<5;o++)
        part[s][o] += __shfl_xor(part[s][o], 32, 64);
    if (l < 32){
      #pragma unroll
      for (int s=0;s<2;s++){
        float* bp = buff + (size_t)(w*64 + 32*s + l)*8;
        bp[0]=part[s][0]; bp[1]=part[s][1]; bp[2]=part[s][2]; bp[3]=part[s][3]; bp[4]=part[s][4];
      }
    }
    __syncthreads();                     // S4: buf + new h1 ready

    if (tid < 320){
      int b = tid / 5, o = tid - 5*b;
      float v = 0.f;
      #pragma unroll
      for (int w8=0; w8<8; w8++) v += buff[(size_t)(w8*64 + b)*8 + o];
      int gb = B0 + b;
      if (o < 2){
        float pr = v + b_pos[o];
        out[(size_t)gb*120 + t*2 + o] = pr;
        posb[b*2 + o] = pr;              // pos for next step
      } else if (o == 2){
        float l11 = fsoftplus(v + b_chol[0]) + 1e-6f;
        out[CB_OFF + (size_t)gb*240 + t*4 + 0] = l11;
        out[CB_OFF + (size_t)gb*240 + t*4 + 1] = 0.f;
      } else if (o == 3){
        out[CB_OFF + (size_t)gb*240 + t*4 + 2] = v + b_chol[1];
      } else {
        out[CB_OFF + (size_t)gb*240 + t*4 + 3] = fsoftplus(v + b_chol[2]) + 1e-6f;
      }
    }
    __syncthreads();                     // S5: posbuf ready for next step
  }
}

// ---------------- host launcher ----------------
extern "C" void kernel_launch(void* const* d_in, const int* in_sizes, int n_in,
                              void* d_out, int out_size, void* d_ws, size_t ws_size,
                              hipStream_t stream)
{
  const float* ctx    = (const float*)d_in[0];
  const float* w_init = (const float*)d_in[2];
  const float* b_init = (const float*)d_in[3];
  const float* w_ih0  = (const float*)d_in[4];
  const float* w_hh0  = (const float*)d_in[5];
  const float* b_ih0  = (const float*)d_in[6];
  const float* b_hh0  = (const float*)d_in[7];
  const float* w_ih1  = (const float*)d_in[8];
  const float* w_hh1  = (const float*)d_in[9];
  const float* b_ih1  = (const float*)d_in[10];
  const float* b_hh1  = (const float*)d_in[11];
  const float* w_pos  = (const float*)d_in[12];
  const float* b_pos  = (const float*)d_in[13];
  const float* w_chol = (const float*)d_in[14];
  const float* b_chol = (const float*)d_in[15];
  char*  ws  = (char*)d_ws;
  float* out = (float*)d_out;

  // allow >64KB dynamic LDS (idempotent; capture-safe host call)
  hipFuncSetAttribute((const void*)decoder_main,
                      hipFuncAttributeMaxDynamicSharedMemorySize, SMEM_BYTES);

  k_pack<<<613, 256, 0, stream>>>(w_init, w_ih0, w_hh0, b_hh0, w_ih1, w_hh1,
                                  b_ih1, b_hh1, w_pos, w_chol, ws);
  decoder_main<<<512, 512, SMEM_BYTES, stream>>>(ctx, b_init, b_ih0, b_pos, b_chol,
                                                 ws, ws + GIWS, out);
}

// Round 5
// 13165.756 us; speedup vs baseline: 1.0462x; 1.0462x over previous
//
#include <hip/hip_runtime.h>
#include <hip/hip_bf16.h>
#include <cstdint>
#include <cstddef>

// ============================================================================
// AutoregressiveDecoder on MI355X — bf16x3 (hi/lo split) MFMA design, v2.
//
// v2 change (R4 post-mortem): gi_ctx lives in 96 persistent VGPRs instead of
// a 100 MB workspace spill. R4 counters showed FETCH_SIZE=26.7GB: the per-XCD
// resident set (32 blk x 192KB gi + 5MB weights) thrashed the 4MB L2, sending
// gi re-reads AND weight re-reads to LLC/HBM (MfmaUtil 22%, dur 14.7ms with a
// 3.2ms MFMA floor). With gi in regs the step-loop weight set (2.36MB) is
// L2-resident. LDS still binds occupancy at 1 blk/CU = 2 waves/SIMD, so up to
// ~512 unified VGPR+AGPR/wave is free; estimate ~224 VGPR + 128 AGPR.
// ============================================================================

typedef __attribute__((ext_vector_type(8)))  short bf16x8;   // 8 bf16
typedef __attribute__((ext_vector_type(16))) float f32x16;
typedef __attribute__((ext_vector_type(4)))  float f32x4;
typedef unsigned short ushort_t;
typedef unsigned int   uint32;

#define MFMA_BF16(A,B,C) __builtin_amdgcn_mfma_f32_32x32x16_bf16(A,B,C,0,0,0)
#define MMA3(ACC, AH, AL, BH, BL)            \
  ACC = MFMA_BF16(AH, BH, ACC);              \
  ACC = MFMA_BF16(AH, BL, ACC);              \
  ACC = MFMA_BF16(AL, BH, ACC);

#define TSTEPS 60
#define CB_OFF 3932160          // cholesky base offset in d_out (32768*60*2)

// ---- workspace layout (bytes) ----
#define WPK0 0u                 // w_hh0 packed  24*16*2048 = 786432
#define WPK1 786432u            // w_ih1 packed
#define WPK2 1572864u           // w_hh1 packed
#define WPKI 2359296u           // w_init packed 16*32*2048 = 1048576
#define WPKG 3407872u           // w_ih0[:,2:] packed 24*32*2048 = 1572864
#define JCON 4980736u           // jconst[768] float4: {b_hh0, wp0, wp1, w4}
#define OUTW 4993024u           // outw[256][8] f32
#define NTWO 5001216u           // n2[256] = b_hh1[512+k]
// total ws requirement: ~5.0 MB (no gi spill in v2)

// ---- LDS layout (bytes) ----
#define OFF_H0 0                // h0 state frags: [c16][p2][s2][lane64][16B] = 65536
#define OFF_H1 65536
#define OFF_BUF 131072          // reduce buf [8][64][8] f32 = 16384
#define OFF_POS 147456          // posbuf [64][2] f32 = 512
#define SMEM_BYTES 147968

// ---------------- helpers ----------------
__device__ __forceinline__ ushort_t f2bf(float x){
  uint32 u = __builtin_bit_cast(uint32, x);
  u += 0x7fffu + ((u >> 16) & 1u);
  return (ushort_t)(u >> 16);
}
__device__ __forceinline__ float bf2f(ushort_t b){
  uint32 u = ((uint32)b) << 16;
  return __builtin_bit_cast(float, u);
}
__device__ __forceinline__ void zero16(f32x16& a){
  #pragma unroll
  for (int i=0;i<16;i++) a[i] = 0.f;
}

#define LOG2E 1.44269504088896340736f
#define LN2   0.69314718055994530942f
__device__ __forceinline__ float fexp2(float x){ return __builtin_amdgcn_exp2f(x); }
__device__ __forceinline__ float flog2(float x){ return __builtin_amdgcn_logf(x); }
__device__ __forceinline__ float frcp (float x){ return __builtin_amdgcn_rcpf(x); }
__device__ __forceinline__ float fsig(float x){ return frcp(1.f + fexp2(-LOG2E*x)); }
__device__ __forceinline__ float ftanh(float x){
  float ax = fabsf(x);
  float e  = fexp2(-2.f*LOG2E*ax);
  float t  = (1.f - e)*frcp(1.f + e);
  return copysignf(t, x);
}
__device__ __forceinline__ float fsoftplus(float x){
  float ax = fabsf(x);
  return fmaxf(x, 0.f) + LN2*flog2(1.f + fexp2(-LOG2E*ax));
}

// ---------------- weight packing ----------------
// frag-linear layout: [t][c][p(hi/lo)][lane][8 bf16]; A-frag(lane l) covers
// row j = 32t + (l&31), k = 16c + (l>>5)*8 + r.
__device__ __forceinline__ void pack_unit(const float* __restrict__ src, int stride, int colOff,
                                          char* __restrict__ dst, int NC, int ncLog, int v)
{
  int l = v & 63;
  int c = (v >> 6) & (NC-1);
  int t = v >> (6 + ncLog);
  int j  = 32*t + (l & 31);
  int k0 = 16*c + ((l >> 5) << 3);
  const float* s = src + (size_t)j*stride + colOff + k0;
  uint32 hp[4], lp[4];
  #pragma unroll
  for (int i=0;i<4;i++){
    float x0 = s[2*i], x1 = s[2*i+1];
    ushort_t h0_ = f2bf(x0), h1_ = f2bf(x1);
    ushort_t l0_ = f2bf(x0 - bf2f(h0_)), l1_ = f2bf(x1 - bf2f(h1_));
    hp[i] = (uint32)h0_ | ((uint32)h1_ << 16);
    lp[i] = (uint32)l0_ | ((uint32)l1_ << 16);
  }
  char* d = dst + ((size_t)(t*NC + c))*2048 + (size_t)l*16;
  *(uint4*)d          = make_uint4(hp[0],hp[1],hp[2],hp[3]);
  *(uint4*)(d + 1024) = make_uint4(lp[0],lp[1],lp[2],lp[3]);
}

__global__ void k_pack(const float* __restrict__ w_init, const float* __restrict__ w_ih0,
                       const float* __restrict__ w_hh0, const float* __restrict__ b_hh0,
                       const float* __restrict__ w_ih1, const float* __restrict__ w_hh1,
                       const float* __restrict__ b_ih1, const float* __restrict__ b_hh1,
                       const float* __restrict__ w_pos, const float* __restrict__ w_chol,
                       char* __restrict__ ws)
{
  int u = blockIdx.x*256 + threadIdx.x;
  if (u < 73728){                       // 3x (768x256) GRU weights
    int seg = u / 24576; int v = u % 24576;
    const float* src = (seg==0) ? w_hh0 : ((seg==1) ? w_ih1 : w_hh1);
    char* dst = ws + ((seg==0) ? WPK0 : ((seg==1) ? WPK1 : WPK2));
    pack_unit(src, 256, 0, dst, 16, 4, v);
  } else if (u < 106496){               // w_init 512x512
    pack_unit(w_init, 512, 0, ws + WPKI, 32, 5, u - 73728);
  } else if (u < 155648){               // w_ih0[:,2:514] 768x512
    pack_unit(w_ih0, 514, 2, ws + WPKG, 32, 5, u - 106496);
  } else if (u < 156416){               // jconst
    int j = u - 155648;
    float w4 = (j < 512) ? (b_ih1[j] + b_hh1[j]) : b_ih1[j];
    ((float4*)(ws + JCON))[j] =
        make_float4(b_hh0[j], w_ih0[(size_t)j*514 + 0], w_ih0[(size_t)j*514 + 1], w4);
  } else if (u < 156672){               // outw
    int k = u - 156416;
    ((float4*)(ws + OUTW))[2*k]   = make_float4(w_pos[k], w_pos[256+k], w_chol[k], w_chol[256+k]);
    ((float4*)(ws + OUTW))[2*k+1] = make_float4(w_chol[512+k], 0.f, 0.f, 0.f);
  } else if (u < 156928){               // n2 = b_hh1 n-part
    int k = u - 156672;
    ((float*)(ws + NTWO))[k] = b_hh1[512+k];
  }
}

// ---------------- main-kernel building blocks ----------------

// GEMM over NCHUNK k-chunks: A from packed global weights (tiles w, w+8, ...),
// B hi/lo frags from LDS at sbase. acc[i][s] += sum_k W.hi/lo * H.hi/lo.
template<int NTILE, int NCHUNK>
__device__ __forceinline__ void gemm_frag(const char* __restrict__ apk, int w, int l,
                                          const char* __restrict__ sbase,
                                          f32x16 (&acc)[NTILE][2])
{
  #pragma unroll 4
  for (int c=0;c<NCHUNK;c++){
    bf16x8 A[NTILE][2];
    #pragma unroll
    for (int i=0;i<NTILE;i++){
      const char* p = apk + ((size_t)((w+8*i)*NCHUNK + c))*2048 + (size_t)l*16;
      A[i][0] = *(const bf16x8*)p;
      A[i][1] = *(const bf16x8*)(p + 1024);
    }
    bf16x8 Bf[2][2];
    #pragma unroll
    for (int s=0;s<2;s++)
      #pragma unroll
      for (int p2=0;p2<2;p2++)
        Bf[s][p2] = *(const bf16x8*)(sbase + ((c*2+p2)*2+s)*1024 + l*16);
    #pragma unroll
    for (int i=0;i<NTILE;i++)
      #pragma unroll
      for (int s=0;s<2;s++){
        MMA3(acc[i][s], A[i][0], A[i][1], Bf[s][0], Bf[s][1]);
      }
  }
}

// read this wave's own state slab back in D-layout (f32 = hi + lo)
__device__ __forceinline__ void readback(const char* __restrict__ hbase, int w, int l,
                                         f32x16 (&ho)[2])
{
  const int L = l >> 5, l31 = l & 31;
  #pragma unroll
  for (int s=0;s<2;s++)
    #pragma unroll
    for (int g=0;g<4;g++){
      int cg = 2*w + (g>>1);
      int lane2 = l31 + 32*(g&1);
      const char* ph = hbase + ((cg*2+0)*2 + s)*1024 + lane2*16 + 8*L;
      const char* pl = hbase + ((cg*2+1)*2 + s)*1024 + lane2*16 + 8*L;
      uint2 hb = *(const uint2*)ph;
      uint2 lb = *(const uint2*)pl;
      ho[s][4*g+0] = bf2f((ushort_t)(hb.x & 0xffff)) + bf2f((ushort_t)(lb.x & 0xffff));
      ho[s][4*g+1] = bf2f((ushort_t)(hb.x >> 16))    + bf2f((ushort_t)(lb.x >> 16));
      ho[s][4*g+2] = bf2f((ushort_t)(hb.y & 0xffff)) + bf2f((ushort_t)(lb.y & 0xffff));
      ho[s][4*g+3] = bf2f((ushort_t)(hb.y >> 16))    + bf2f((ushort_t)(lb.y >> 16));
    }
}

// convert new-h D-layout regs -> hi/lo B-frags, write wave's own state chunks.
__device__ __forceinline__ void write_state(char* __restrict__ hbase, int w, int l,
                                            const f32x16 (&hn)[2])
{
  const int L = l >> 5;
  #pragma unroll
  for (int s=0;s<2;s++){
    float loc[16], sw[16];
    #pragma unroll
    for (int q=0;q<16;q++){ loc[q] = hn[s][q]; sw[q] = __shfl_xor(loc[q], 32, 64); }
    #pragma unroll
    for (int c=0;c<2;c++){
      float v[8];
      if (L == 0){
        #pragma unroll
        for (int r=0;r<8;r++){ int q = (r&3) + 8*c;     v[r] = (r<4)  ? loc[q] : sw[q]; }
      } else {
        #pragma unroll
        for (int r=0;r<8;r++){ int q = (r&3) + 8*c + 4; v[r] = (r>=4) ? loc[q] : sw[q]; }
      }
      uint32 hp[4], lp[4];
      #pragma unroll
      for (int i=0;i<4;i++){
        ushort_t h0_ = f2bf(v[2*i]), h1_ = f2bf(v[2*i+1]);
        ushort_t l0_ = f2bf(v[2*i] - bf2f(h0_)), l1_ = f2bf(v[2*i+1] - bf2f(h1_));
        hp[i] = (uint32)h0_ | ((uint32)h1_ << 16);
        lp[i] = (uint32)l0_ | ((uint32)l1_ << 16);
      }
      int cg = 2*w + c;
      *(uint4*)(hbase + ((cg*2+0)*2+s)*1024 + l*16) = make_uint4(hp[0],hp[1],hp[2],hp[3]);
      *(uint4*)(hbase + ((cg*2+1)*2+s)*1024 + l*16) = make_uint4(lp[0],lp[1],lp[2],lp[3]);
    }
  }
}

// ---------------- the persistent decoder kernel ----------------
__global__ __launch_bounds__(512, 2) void decoder_main(
    const float* __restrict__ ctx,
    const float* __restrict__ b_init,
    const float* __restrict__ b_ih0,
    const float* __restrict__ b_pos,
    const float* __restrict__ b_chol,
    const char*  __restrict__ ws,
    float*       __restrict__ out)
{
  extern __shared__ char smem[];
  const int tid = threadIdx.x;
  const int w   = tid >> 6;
  const int l   = tid & 63;
  const int L   = l >> 5;
  const int l31 = l & 31;
  const int blk = blockIdx.x;
  const int B0  = blk * 64;
  const float4* jconst = (const float4*)(ws + JCON);
  const float4* outw   = (const float4*)(ws + OUTW);
  const float*  n2c    = (const float*)(ws + NTWO);
  float* posb = (float*)(smem + OFF_POS);
  float* buff = (float*)(smem + OFF_BUF);

  // ---- prologue A: stage ctx hi/lo B-frags into LDS (aliases state area) ----
  #pragma unroll
  for (int ci=0; ci<4; ci++){
    int c = w + 8*ci;
    #pragma unroll
    for (int s=0;s<2;s++){
      const float* src = ctx + (size_t)(B0 + 32*s + l31)*512 + 16*c + 8*L;
      float4 a0 = *(const float4*)src;
      float4 a1 = *(const float4*)(src + 4);
      float xs[8] = {a0.x,a0.y,a0.z,a0.w,a1.x,a1.y,a1.z,a1.w};
      uint32 hp[4], lp[4];
      #pragma unroll
      for (int i=0;i<4;i++){
        ushort_t h0_ = f2bf(xs[2*i]), h1_ = f2bf(xs[2*i+1]);
        ushort_t l0_ = f2bf(xs[2*i] - bf2f(h0_)), l1_ = f2bf(xs[2*i+1] - bf2f(h1_));
        hp[i] = (uint32)h0_ | ((uint32)h1_ << 16);
        lp[i] = (uint32)l0_ | ((uint32)l1_ << 16);
      }
      *(uint4*)(smem + ((c*2+0)*2 + s)*1024 + l*16) = make_uint4(hp[0],hp[1],hp[2],hp[3]);
      *(uint4*)(smem + ((c*2+1)*2 + s)*1024 + l*16) = make_uint4(lp[0],lp[1],lp[2],lp[3]);
    }
  }
  __syncthreads();

  // ---- prologue B: hid = tanh(ctx @ w_init.T + b_init) ----
  f32x16 hD0[2], hD1[2];
  {
    f32x16 aH[2][2];
    zero16(aH[0][0]); zero16(aH[0][1]); zero16(aH[1][0]); zero16(aH[1][1]);
    gemm_frag<2,32>(ws + WPKI, w, l, smem, aH);
    #pragma unroll
    for (int ti=0; ti<2; ti++)
      #pragma unroll
      for (int s=0;s<2;s++)
        #pragma unroll
        for (int g=0;g<4;g++)
          #pragma unroll
          for (int e=0;e<4;e++){
            int kq = 4*L + e + 8*g;
            int j  = 32*(w + 8*ti) + kq;
            float v = ftanh(aH[ti][s][4*g+e] + b_init[j]);
            if (ti==0) hD0[s][4*g+e] = v; else hD1[s][4*g+e] = v;
          }
  }

  // ---- prologue C: gi_ctx = ctx @ w_ih0[:,2:].T + b_ih0 -> PERSISTENT REGS ----
  f32x16 gi[3][2];                      // 96 VGPRs, live across all 60 steps
  {
    #pragma unroll
    for (int i=0;i<3;i++){ zero16(gi[i][0]); zero16(gi[i][1]); }
    gemm_frag<3,32>(ws + WPKG, w, l, smem, gi);
    #pragma unroll
    for (int ti=0; ti<3; ti++)
      #pragma unroll
      for (int s=0;s<2;s++)
        #pragma unroll
        for (int g=0;g<4;g++)
          #pragma unroll
          for (int e=0;e<4;e++){
            int kq = 4*L + e + 8*g;
            int j  = 32*(w + 8*ti) + kq;
            gi[ti][s][4*g+e] += b_ih0[j];
          }
  }
  __syncthreads();                       // all ctx-frag reads done

  write_state(smem + OFF_H0, w, l, hD0); // state overwrites ctx area
  write_state(smem + OFF_H1, w, l, hD1);
  if (tid < 128) posb[tid] = 0.f;
  __syncthreads();

  // ---- 60 autoregressive steps ----
  for (int t=0; t<TSTEPS; t++){
    // GRU0: gh0 = w_hh0 @ h0^T
    f32x16 g0[3][2];
    #pragma unroll
    for (int i=0;i<3;i++){ zero16(g0[i][0]); zero16(g0[i][1]); }
    gemm_frag<3,16>(ws + WPK0, w, l, smem + OFF_H0, g0);

    f32x16 ho[2];
    readback(smem + OFF_H0, w, l, ho);
    float p0v[2], p1v[2];
    #pragma unroll
    for (int s=0;s<2;s++){
      float2 pp = *(const float2*)(posb + (32*s + l31)*2);
      p0v[s] = pp.x; p1v[s] = pp.y;
    }

    f32x16 hn0[2];
    #pragma unroll
    for (int g=0;g<4;g++)
      #pragma unroll
      for (int e=0;e<4;e++){
        int kq = 4*L + e + 8*g;
        int jr = 32*w + kq;
        float4 jcr = jconst[jr], jcz = jconst[256+jr], jcn = jconst[512+jr];
        #pragma unroll
        for (int s=0;s<2;s++){
          int q = 4*g + e;
          float gi_r = gi[0][s][q] + jcr.y*p0v[s] + jcr.z*p1v[s];
          float gi_z = gi[1][s][q] + jcz.y*p0v[s] + jcz.z*p1v[s];
          float gi_n = gi[2][s][q] + jcn.y*p0v[s] + jcn.z*p1v[s];
          float r = fsig(gi_r + g0[0][s][q] + jcr.x);
          float z = fsig(gi_z + g0[1][s][q] + jcz.x);
          float n = ftanh(gi_n + r*(g0[2][s][q] + jcn.x));
          hn0[s][q] = (1.f - z)*n + z*ho[s][q];
        }
      }
    __syncthreads();                     // S1: all h0/pos reads done
    write_state(smem + OFF_H0, w, l, hn0);
    __syncthreads();                     // S2: new h0 visible

    // GRU1: gi1 = w_ih1 @ h0new^T, gh1 = w_hh1 @ h1^T (r,z summed; n split)
    f32x16 aR[2], aZ[2], aNi[2], aNh[2];
    zero16(aR[0]); zero16(aR[1]); zero16(aZ[0]); zero16(aZ[1]);
    zero16(aNi[0]); zero16(aNi[1]); zero16(aNh[0]); zero16(aNh[1]);
    {
      const char* pk1 = ws + WPK1;
      const char* pk2 = ws + WPK2;
      #pragma unroll 4
      for (int c=0;c<16;c++){
        bf16x8 A1[3][2], A2[3][2];
        #pragma unroll
        for (int i=0;i<3;i++){
          size_t o = ((size_t)((w+8*i)*16 + c))*2048 + (size_t)l*16;
          A1[i][0] = *(const bf16x8*)(pk1+o); A1[i][1] = *(const bf16x8*)(pk1+o+1024);
          A2[i][0] = *(const bf16x8*)(pk2+o); A2[i][1] = *(const bf16x8*)(pk2+o+1024);
        }
        bf16x8 B0f[2][2], B1f[2][2];
        #pragma unroll
        for (int s=0;s<2;s++)
          #pragma unroll
          for (int p2=0;p2<2;p2++){
            B0f[s][p2] = *(const bf16x8*)(smem + OFF_H0 + ((c*2+p2)*2+s)*1024 + l*16);
            B1f[s][p2] = *(const bf16x8*)(smem + OFF_H1 + ((c*2+p2)*2+s)*1024 + l*16);
          }
        #pragma unroll
        for (int s=0;s<2;s++){
          MMA3(aR[s],  A1[0][0], A1[0][1], B0f[s][0], B0f[s][1]);
          MMA3(aR[s],  A2[0][0], A2[0][1], B1f[s][0], B1f[s][1]);
          MMA3(aZ[s],  A1[1][0], A1[1][1], B0f[s][0], B0f[s][1]);
          MMA3(aZ[s],  A2[1][0], A2[1][1], B1f[s][0], B1f[s][1]);
          MMA3(aNi[s], A1[2][0], A1[2][1], B0f[s][0], B0f[s][1]);
          MMA3(aNh[s], A2[2][0], A2[2][1], B1f[s][0], B1f[s][1]);
        }
      }
    }

    f32x16 h1o[2];
    readback(smem + OFF_H1, w, l, h1o);
    f32x16 hn1[2];
    #pragma unroll
    for (int g=0;g<4;g++)
      #pragma unroll
      for (int e=0;e<4;e++){
        int kq = 4*L + e + 8*g;
        int k  = 32*w + kq;
        float4 jcr = jconst[k], jcz = jconst[256+k], jcn = jconst[512+k];
        float nb = n2c[k];
        #pragma unroll
        for (int s=0;s<2;s++){
          int q = 4*g + e;
          float r = fsig(aR[s][q] + jcr.w);
          float z = fsig(aZ[s][q] + jcz.w);
          float n = ftanh(aNi[s][q] + jcn.w + r*(aNh[s][q] + nb));
          hn1[s][q] = (1.f - z)*n + z*h1o[s][q];
        }
      }
    __syncthreads();                     // S3: all h1 reads done
    write_state(smem + OFF_H1, w, l, hn1);

    // output head partials: pred(2) + chol-z(3) per row
    float part[2][5];
    #pragma unroll
    for (int s=0;s<2;s++){ part[s][0]=part[s][1]=part[s][2]=part[s][3]=part[s][4]=0.f; }
    #pragma unroll
    for (int g=0;g<4;g++)
      #pragma unroll
      for (int e=0;e<4;e++){
        int kq = 4*L + e + 8*g;
        int k  = 32*w + kq;
        float4 o0 = outw[2*k], o1 = outw[2*k+1];
        #pragma unroll
        for (int s=0;s<2;s++){
          float h = hn1[s][4*g+e];
          part[s][0] += h*o0.x; part[s][1] += h*o0.y; part[s][2] += h*o0.z;
          part[s][3] += h*o0.w; part[s][4] += h*o1.x;
        }
      }
    #pragma unroll
    for (int s=0;s<2;s++)
      #pragma unroll
      for (int o=0;o<5;o++)
        part[s][o] += __shfl_xor(part[s][o], 32, 64);
    if (l < 32){
      #pragma unroll
      for (int s=0;s<2;s++){
        float* bp = buff + (size_t)(w*64 + 32*s + l)*8;
        bp[0]=part[s][0]; bp[1]=part[s][1]; bp[2]=part[s][2]; bp[3]=part[s][3]; bp[4]=part[s][4];
      }
    }
    __syncthreads();                     // S4: buf + new h1 ready

    if (tid < 320){
      int b = tid / 5, o = tid - 5*b;
      float v = 0.f;
      #pragma unroll
      for (int w8=0; w8<8; w8++) v += buff[(size_t)(w8*64 + b)*8 + o];
      int gb = B0 + b;
      if (o < 2){
        float pr = v + b_pos[o];
        out[(size_t)gb*120 + t*2 + o] = pr;
        posb[b*2 + o] = pr;              // pos for next step
      } else if (o == 2){
        float l11 = fsoftplus(v + b_chol[0]) + 1e-6f;
        out[CB_OFF + (size_t)gb*240 + t*4 + 0] = l11;
        out[CB_OFF + (size_t)gb*240 + t*4 + 1] = 0.f;
      } else if (o == 3){
        out[CB_OFF + (size_t)gb*240 + t*4 + 2] = v + b_chol[1];
      } else {
        out[CB_OFF + (size_t)gb*240 + t*4 + 3] = fsoftplus(v + b_chol[2]) + 1e-6f;
      }
    }
    __syncthreads();                     // S5: posbuf ready for next step
  }
}

// ---------------- host launcher ----------------
extern "C" void kernel_launch(void* const* d_in, const int* in_sizes, int n_in,
                              void* d_out, int out_size, void* d_ws, size_t ws_size,
                              hipStream_t stream)
{
  const float* ctx    = (const float*)d_in[0];
  const float* w_init = (const float*)d_in[2];
  const float* b_init = (const float*)d_in[3];
  const float* w_ih0  = (const float*)d_in[4];
  const float* w_hh0  = (const float*)d_in[5];
  const float* b_ih0  = (const float*)d_in[6];
  const float* b_hh0  = (const float*)d_in[7];
  const float* w_ih1  = (const float*)d_in[8];
  const float* w_hh1  = (const float*)d_in[9];
  const float* b_ih1  = (const float*)d_in[10];
  const float* b_hh1  = (const float*)d_in[11];
  const float* w_pos  = (const float*)d_in[12];
  const float* b_pos  = (const float*)d_in[13];
  const float* w_chol = (const float*)d_in[14];
  const float* b_chol = (const float*)d_in[15];
  char*  ws  = (char*)d_ws;
  float* out = (float*)d_out;

  // allow >64KB dynamic LDS (idempotent; capture-safe host call)
  hipFuncSetAttribute((const void*)decoder_main,
                      hipFuncAttributeMaxDynamicSharedMemorySize, SMEM_BYTES);

  k_pack<<<613, 256, 0, stream>>>(w_init, w_ih0, w_hh0, b_hh0, w_ih1, w_hh1,
                                  b_ih1, b_hh1, w_pos, w_chol, ws);
  decoder_main<<<512, 512, SMEM_BYTES, stream>>>(ctx, b_init, b_ih0, b_pos, b_chol,
                                                 ws, out);
}